// Round 8
// baseline (421.906 us; speedup 1.0000x reference)
//
#include <hip/hip_runtime.h>
#include <hip/hip_bf16.h>

#define B_ 16
#define S_ 1024
#define L_ 2048
#define H_ 32

typedef float f2v __attribute__((ext_vector_type(2)));
typedef float f4v __attribute__((ext_vector_type(4)));

// packed dual-FMA (VOP3P v_pk_fma_f32, gfx90a+/gfx950)
static __device__ __forceinline__ f2v pkfma(f2v a, f2v b, f2v c) {
    f2v d;
    asm("v_pk_fma_f32 %0, %1, %2, %3" : "=v"(d) : "v"(a), "v"(b), "v"(c));
    return d;
}
static __device__ __forceinline__ f2v pkadd(f2v a, f2v b) {
    f2v d;
    asm("v_pk_add_f32 %0, %1, %2" : "=v"(d) : "v"(a), "v"(b));
    return d;
}
// v_permlane32_swap_b32: UPPER half of a <-> LOWER half of b
//   new_a[32:63] = b[0:31]; new_b[0:31] = a[32:63]  (verified: R7 fail + LLVM doc)
static __device__ __forceinline__ void pl32swap(float& a, float& b) {
    asm("v_permlane32_swap_b32 %0, %1" : "+v"(a), "+v"(b));
}

// ===== fully fused: per block b -> LSTM scan, attn(v1), attn(v2), final MLP =====
__global__ __launch_bounds__(64) void fused_net(
    const float* __restrict__ x,      // (16,1024,3)
    const float* __restrict__ v1,     // (16,2049,3)
    const float* __restrict__ v2,
    const float* __restrict__ attn_w, // (1,6)
    const float* __restrict__ fc1_w,  // (16,3)
    const float* __restrict__ fc1_b,  // (16,)
    const float* __restrict__ w_ih,   // (128,16)
    const float* __restrict__ w_hh,   // (128,32)
    const float* __restrict__ b_ih,   // (128,)
    const float* __restrict__ b_hh,   // (128,)
    const float* __restrict__ fc2_w,  // (16,38)
    const float* __restrict__ fc2_b,  // (16,)
    const float* __restrict__ fc3_w,  // (3,16)
    const float* __restrict__ fc3_b,  // (3,)
    float* __restrict__ h_ws,         // (16,1024,32) scratch
    float* __restrict__ out)          // (16,1024,3)
{
    const int b  = blockIdx.x;
    const int l  = threadIdx.x;
    const int j  = l & 31;
    const int hi = l >> 5;
    const int r0 = hi ? (32 + j) : j;          // f : i
    const int r1 = hi ? (96 + j) : (64 + j);   // o : g

    __shared__ float lds_x[S_ * 3];            // x staging; reused as weight buf for MLP
    __shared__ float lds_h[64];                // double-buffered h

    {   // stage x[b] (12 KiB); single wave -> in-order DS, no barrier needed
        const f4v* src = (const f4v*)(x + (size_t)b * (S_ * 3));
        f4v* dst = (f4v*)lds_x;
#pragma unroll
        for (int m = 0; m < 12; ++m) dst[l + 64 * m] = src[l + 64 * m];
    }
    if (l < 32) lds_h[l] = 0.f;                // buffer 0 = h_{-1}

    const float CE = -1.44269504f;             // -log2(e): sigma(x)=rcp(1+exp2(x*CE))
    const float k1 = hi ? CE : 2.f * CE;       // lo lanes' gate1 is g -> sigma(2g)

    // recurrent weight rows, packed f2v, PRE-SCALED so acc == exp2-ready argument
    f2v wh0[16], wh1[16];
    {
        const f4v* p0 = (const f4v*)(w_hh + r0 * H_);
        const f4v* p1 = (const f4v*)(w_hh + r1 * H_);
#pragma unroll
        for (int m = 0; m < 8; ++m) {
            f4v a = p0[m];
            wh0[2*m]   = f2v{a.x * CE, a.y * CE};
            wh0[2*m+1] = f2v{a.z * CE, a.w * CE};
            f4v c2 = p1[m];
            wh1[2*m]   = f2v{c2.x * k1, c2.y * k1};
            wh1[2*m+1] = f2v{c2.z * k1, c2.w * k1};
        }
    }
    // fold fc1: W = w_ih@fc1_w, bb = w_ih@fc1_b + b_ih + b_hh  (then pre-scale)
    float W00 = 0, W01 = 0, W02 = 0, W10 = 0, W11 = 0, W12 = 0, bb0, bb1;
    {
        float s0 = 0, s1 = 0;
#pragma unroll
        for (int k = 0; k < 16; ++k) {
            float wi0 = w_ih[r0 * 16 + k], wi1 = w_ih[r1 * 16 + k];
            float f0 = fc1_w[k * 3 + 0], f1 = fc1_w[k * 3 + 1], f2 = fc1_w[k * 3 + 2];
            float fb = fc1_b[k];
            W00 = fmaf(wi0, f0, W00); W01 = fmaf(wi0, f1, W01); W02 = fmaf(wi0, f2, W02);
            s0  = fmaf(wi0, fb, s0);
            W10 = fmaf(wi1, f0, W10); W11 = fmaf(wi1, f1, W11); W12 = fmaf(wi1, f2, W12);
            s1  = fmaf(wi1, fb, s1);
        }
        bb0 = (s0 + b_ih[r0] + b_hh[r0]) * CE;
        bb1 = (s1 + b_ih[r1] + b_hh[r1]) * k1;
        W00 *= CE; W01 *= CE; W02 *= CE;
        W10 *= k1; W11 *= k1; W12 *= k1;
    }

    float c = 0.f;
    float* hob = h_ws + ((size_t)b << 15);

    // --------------- LSTM scan: no barriers, no DS cross-lane ---------------
    // lanes lo: s0=sig(i), s1=sig(2g);  lanes hi: s0=sig(f), s1=sig(o)
    // swap(A0=s0,B0=s1): A0.hi <- sig(2g), B0.lo <- sig(f)
    // swap(C0=s1,D0=s0): C0.hi <- sig(i),  D0.lo <- sig(o)
#define STEP(T, RB, WB) do {                                                          \
        float x0 = lds_x[3*(T)], x1 = lds_x[3*(T)+1], x2 = lds_x[3*(T)+2];            \
        f2v acc0a = { fmaf(W02,x2, fmaf(W01,x1, fmaf(W00,x0, bb0))), 0.f };           \
        f2v acc1a = { fmaf(W12,x2, fmaf(W11,x1, fmaf(W10,x0, bb1))), 0.f };           \
        f2v acc0b = { 0.f, 0.f };                                                     \
        f2v acc1b = { 0.f, 0.f };                                                     \
        _Pragma("unroll")                                                             \
        for (int m = 0; m < 8; ++m) {                                                 \
            f4v hv = *(const f4v*)&lds_h[(RB) + 4*m];                                 \
            f2v hlo = __builtin_shufflevector(hv, hv, 0, 1);                          \
            f2v hhi = __builtin_shufflevector(hv, hv, 2, 3);                          \
            acc0a = pkfma(wh0[2*m],   hlo, acc0a);                                    \
            acc1a = pkfma(wh1[2*m],   hlo, acc1a);                                    \
            acc0b = pkfma(wh0[2*m+1], hhi, acc0b);                                    \
            acc1b = pkfma(wh1[2*m+1], hhi, acc1b);                                    \
        }                                                                             \
        f2v acc0 = pkadd(acc0a, acc0b);                                               \
        f2v acc1 = pkadd(acc1a, acc1b);                                               \
        float s0 = __builtin_amdgcn_rcpf(1.f + __builtin_amdgcn_exp2f(acc0.x + acc0.y)); \
        float s1 = __builtin_amdgcn_rcpf(1.f + __builtin_amdgcn_exp2f(acc1.x + acc1.y)); \
        float A0 = s0, B0 = s1;                                                       \
        pl32swap(A0, B0);      /* A0.hi=sig(2g), B0.lo=sig(f) */                      \
        float C0 = s1, D0 = s0;                                                       \
        pl32swap(C0, D0);      /* C0.hi=sig(i),  D0.lo=sig(o) */                      \
        float si = hi ? C0 : s0;                                                      \
        float sf = hi ? s0 : B0;                                                      \
        float sg = hi ? A0 : s1;                                                      \
        float so = hi ? s1 : D0;                                                      \
        float tg = fmaf(2.f, sg, -1.f);                                               \
        c = fmaf(sf, c, si * tg);                                                     \
        float tc = fmaf(2.f, __builtin_amdgcn_rcpf(1.f + __builtin_amdgcn_exp2f(c * (2.f*CE))), -1.f); \
        float hval = so * tc;                                                         \
        if (!hi) lds_h[(WB) + j] = hval;                                              \
        else     hob[((T) << 5) + j] = hval;                                          \
    } while (0)

    for (int t = 0; t < S_; t += 2) {
        STEP(t,     0, 32);
        STEP(t + 1, 32, 0);
    }
#undef STEP

    // --------------- attention (softmax over keys is query-independent) ---------------
    float a1v0, a1v1, a1v2, a2v0, a2v1, a2v2;
    {
        const float wk0 = attn_w[3], wk1 = attn_w[4], wk2 = attn_w[5];
#pragma unroll
        for (int sel = 0; sel < 2; ++sel) {
            const float* v = (sel ? v2 : v1) + (size_t)b * ((L_ + 1) * 3);
            float s[32];
            float mx = -3.4e38f;
#pragma unroll
            for (int k = 0; k < 32; ++k) {
                const float* p = v + (l + (k << 6)) * 3;      // key rows 0..2047
                float sc = fmaf(p[2], wk2, fmaf(p[1], wk1, p[0] * wk0));
                s[k] = sc; mx = fmaxf(mx, sc);
            }
#pragma unroll
            for (int o = 1; o < 64; o <<= 1) mx = fmaxf(mx, __shfl_xor(mx, o));

            float den = 0.f, a0 = 0.f, a1 = 0.f, a2 = 0.f;
#pragma unroll
            for (int k = 0; k < 32; ++k) {
                float e = __expf(s[k] - mx);
                const float* p = v + (l + (k << 6) + 1) * 3;  // value rows 1..2048
                den += e;
                a0 = fmaf(e, p[0], a0); a1 = fmaf(e, p[1], a1); a2 = fmaf(e, p[2], a2);
            }
#pragma unroll
            for (int o = 1; o < 64; o <<= 1) {
                den += __shfl_xor(den, o); a0 += __shfl_xor(a0, o);
                a1  += __shfl_xor(a1, o);  a2 += __shfl_xor(a2, o);
            }
            float inv = 1.0f / den;                           // all lanes hold result
            if (sel == 0) { a1v0 = a0 * inv; a1v1 = a1 * inv; a1v2 = a2 * inv; }
            else          { a2v0 = a0 * inv; a2v1 = a1 * inv; a2v2 = a2 * inv; }
        }
    }

    // --------------- final MLP: out = relu([a1,a2,h]@fc2^T+b2)@fc3^T+b3 ---------------
    // reuse lds_x as weight buffer (single wave: in-order DS, safe to overwrite)
    float* ldsw = lds_x;                                      // [0,608) fc2_w, [608,624) fc2_b,
    for (int i = l; i < 608; i += 64) ldsw[i] = fc2_w[i];     // [624,672) fc3_w, [672,675) fc3_b
    if (l < 16) ldsw[608 + l] = fc2_b[l];
    if (l < 48) ldsw[624 + l] = fc3_w[l];
    if (l < 3)  ldsw[672 + l] = fc3_b[l];

    const float* hrow = h_ws + ((size_t)b << 15);
    float* orow = out + (size_t)b * (S_ * 3);
#pragma unroll 1
    for (int q = 0; q < 16; ++q) {
        const int t = l + (q << 6);
        float hv[32];
        {
            const f4v* hp = (const f4v*)(hrow + (t << 5));
#pragma unroll
            for (int m = 0; m < 8; ++m) {
                f4v tv = hp[m];
                hv[4*m] = tv.x; hv[4*m+1] = tv.y; hv[4*m+2] = tv.z; hv[4*m+3] = tv.w;
            }
        }
        float y[16];
#pragma unroll
        for (int u = 0; u < 16; ++u) {
            const float* w = ldsw + u * 38;
            float acc = ldsw[608 + u];
            acc = fmaf(w[0], a1v0, acc); acc = fmaf(w[1], a1v1, acc); acc = fmaf(w[2], a1v2, acc);
            acc = fmaf(w[3], a2v0, acc); acc = fmaf(w[4], a2v1, acc); acc = fmaf(w[5], a2v2, acc);
#pragma unroll
            for (int k = 0; k < 32; ++k) acc = fmaf(w[6 + k], hv[k], acc);
            y[u] = fmaxf(acc, 0.f);
        }
#pragma unroll
        for (int d = 0; d < 3; ++d) {
            float o = ldsw[672 + d];
#pragma unroll
            for (int u = 0; u < 16; ++u) o = fmaf(ldsw[624 + d * 16 + u], y[u], o);
            orow[t * 3 + d] = o;
        }
    }
}

extern "C" void kernel_launch(void* const* d_in, const int* in_sizes, int n_in,
                              void* d_out, int out_size, void* d_ws, size_t ws_size,
                              hipStream_t stream) {
    const float* x      = (const float*)d_in[0];
    const float* v1     = (const float*)d_in[1];
    const float* v2     = (const float*)d_in[2];
    const float* attn_w = (const float*)d_in[3];
    // d_in[4] = attn_b: shift-invariant under softmax, unused
    const float* fc1_w  = (const float*)d_in[5];
    const float* fc1_b  = (const float*)d_in[6];
    const float* w_ih   = (const float*)d_in[7];
    const float* w_hh   = (const float*)d_in[8];
    const float* b_ih   = (const float*)d_in[9];
    const float* b_hh   = (const float*)d_in[10];
    const float* fc2_w  = (const float*)d_in[11];
    const float* fc2_b  = (const float*)d_in[12];
    const float* fc3_w  = (const float*)d_in[13];
    const float* fc3_b  = (const float*)d_in[14];
    float* out = (float*)d_out;
    float* hws = (float*)d_ws;                         // 16*1024*32 floats = 2 MiB

    fused_net<<<16, 64, 0, stream>>>(x, v1, v2, attn_w, fc1_w, fc1_b,
                                     w_ih, w_hh, b_ih, b_hh,
                                     fc2_w, fc2_b, fc3_w, fc3_b, hws, out);
}

// Round 11
// 407.779 us; speedup vs baseline: 1.0346x; 1.0346x over previous
//
#include <hip/hip_runtime.h>
#include <hip/hip_bf16.h>

#define B_ 16
#define S_ 1024
#define L_ 2048
#define H_ 32

typedef float f2v __attribute__((ext_vector_type(2)));
typedef float f4v __attribute__((ext_vector_type(4)));

// packed dual-FMA (VOP3P v_pk_fma_f32, gfx90a+/gfx950)
static __device__ __forceinline__ f2v pkfma(f2v a, f2v b, f2v c) {
    f2v d;
    asm("v_pk_fma_f32 %0, %1, %2, %3" : "=v"(d) : "v"(a), "v"(b), "v"(c));
    return d;
}
static __device__ __forceinline__ f2v pkadd(f2v a, f2v b) {
    f2v d;
    asm("v_pk_add_f32 %0, %1, %2" : "=v"(d) : "v"(a), "v"(b));
    return d;
}

// ============ fused kernel: blocks 0-15 = LSTM scan, 16-47 = attention ============
__global__ __launch_bounds__(64) void fused_attn_lstm(
    const float* __restrict__ x,      // (16,1024,3)
    const float* __restrict__ v1,     // (16,2049,3)
    const float* __restrict__ v2,
    const float* __restrict__ attn_w, // (1,6)
    const float* __restrict__ fc1_w,  // (16,3)
    const float* __restrict__ fc1_b,  // (16,)
    const float* __restrict__ w_ih,   // (128,16)
    const float* __restrict__ w_hh,   // (128,32)
    const float* __restrict__ b_ih,   // (128,)
    const float* __restrict__ b_hh,   // (128,)
    float* __restrict__ A,            // (2,16,3) ws
    float* __restrict__ h_out)        // (16,1024,32) ws
{
    const int blk = blockIdx.x;
    const int l   = threadIdx.x;

    if (blk >= 16) {
        // ---------------- attention (i-independent softmax over keys) ----------------
        const int idx = blk - 16;
        const int b = idx & 15, sel = idx >> 4;
        const float* v = (sel ? v2 : v1) + (size_t)b * ((L_ + 1) * 3);
        const float wk0 = attn_w[3], wk1 = attn_w[4], wk2 = attn_w[5];

        float s[32];
        float mx = -3.4e38f;
#pragma unroll
        for (int k = 0; k < 32; ++k) {
            const float* p = v + (l + (k << 6)) * 3;      // key rows 0..2047, coalesced
            float sc = fmaf(p[2], wk2, fmaf(p[1], wk1, p[0] * wk0));
            s[k] = sc; mx = fmaxf(mx, sc);
        }
#pragma unroll
        for (int o = 1; o < 64; o <<= 1) mx = fmaxf(mx, __shfl_xor(mx, o));

        float den = 0.f, a0 = 0.f, a1 = 0.f, a2 = 0.f;
#pragma unroll
        for (int k = 0; k < 32; ++k) {
            float e = __expf(s[k] - mx);
            const float* p = v + (l + (k << 6) + 1) * 3;  // value rows 1..2048
            den += e;
            a0 = fmaf(e, p[0], a0); a1 = fmaf(e, p[1], a1); a2 = fmaf(e, p[2], a2);
        }
#pragma unroll
        for (int o = 1; o < 64; o <<= 1) {
            den += __shfl_xor(den, o); a0 += __shfl_xor(a0, o);
            a1  += __shfl_xor(a1, o);  a2 += __shfl_xor(a2, o);
        }
        if (l == 0) {
            float inv = 1.0f / den;
            float* dst = A + sel * 48 + b * 3;
            dst[0] = a0 * inv; dst[1] = a1 * inv; dst[2] = a2 * inv;
        }
        return;
    }

    // ---------------- LSTM scan: one batch per 64-lane wave, NO barriers ----------------
    // lane l: j=l&31, hi=l>>5.  hi=0 -> rows (i_j, g_j); hi=1 -> rows (f_j, o_j)
    const int b  = blk;
    const int j  = l & 31;
    const int hi = l >> 5;
    const int r0 = hi ? (32 + j) : j;          // f : i
    const int r1 = hi ? (96 + j) : (64 + j);   // o : g

    __shared__ float lds_h[64];                // double-buffered h (ONLY LDS use)
    if (l < 32) lds_h[l] = 0.f;                // buffer 0 = h_{-1}

    // recurrent weight rows, packed as float2 pairs for v_pk_fma_f32 (UNSCALED - R6 verified)
    f2v wh0[16], wh1[16];
    {
        const f4v* p0 = (const f4v*)(w_hh + r0 * H_);
        const f4v* p1 = (const f4v*)(w_hh + r1 * H_);
#pragma unroll
        for (int m = 0; m < 8; ++m) {
            f4v a = p0[m];
            wh0[2*m]   = __builtin_shufflevector(a, a, 0, 1);
            wh0[2*m+1] = __builtin_shufflevector(a, a, 2, 3);
            f4v c2 = p1[m];
            wh1[2*m]   = __builtin_shufflevector(c2, c2, 0, 1);
            wh1[2*m+1] = __builtin_shufflevector(c2, c2, 2, 3);
        }
    }

    // fold fc1 into input path: W = w_ih@fc1_w (2 rows/lane), bb = w_ih@fc1_b + b_ih + b_hh
    float W00 = 0, W01 = 0, W02 = 0, W10 = 0, W11 = 0, W12 = 0, bb0, bb1;
    {
        float s0 = 0, s1 = 0;
#pragma unroll
        for (int k = 0; k < 16; ++k) {
            float wi0 = w_ih[r0 * 16 + k], wi1 = w_ih[r1 * 16 + k];
            float f0 = fc1_w[k * 3 + 0], f1 = fc1_w[k * 3 + 1], f2 = fc1_w[k * 3 + 2];
            float fb = fc1_b[k];
            W00 = fmaf(wi0, f0, W00); W01 = fmaf(wi0, f1, W01); W02 = fmaf(wi0, f2, W02);
            s0  = fmaf(wi0, fb, s0);
            W10 = fmaf(wi1, f0, W10); W11 = fmaf(wi1, f1, W11); W12 = fmaf(wi1, f2, W12);
            s1  = fmaf(wi1, fb, s1);
        }
        bb0 = s0 + b_ih[r0] + b_hh[r0];
        bb1 = s1 + b_ih[r1] + b_hh[r1];
    }

    const float CE = -1.44269504f;             // -log2(e): sigma(x)=rcp(1+exp2(x*CE))
    const float c1 = hi ? CE : 2.f * CE;       // hi=0 lane: a1 is g -> sigma(2g) for tanh
    float c = 0.f;
    float* hob = h_out + ((size_t)b << 15);

    // x comes from GLOBAL, prefetched one 4-step group ahead (off the DS pipe entirely)
    const f4v* xg = (const f4v*)(x + (size_t)b * (S_ * 3));  // 256 groups x 3 f4v

#define STEP(T, RB, WB, X0, X1, X2) do {                                              \
        f2v acc0a = { fmaf(W02,(X2), fmaf(W01,(X1), fmaf(W00,(X0), bb0))), 0.f };     \
        f2v acc1a = { fmaf(W12,(X2), fmaf(W11,(X1), fmaf(W10,(X0), bb1))), 0.f };     \
        f2v acc0b = { 0.f, 0.f };                                                     \
        f2v acc1b = { 0.f, 0.f };                                                     \
        _Pragma("unroll")                                                             \
        for (int m = 0; m < 8; ++m) {                                                 \
            f4v hv = *(const f4v*)&lds_h[(RB) + 4*m];                                 \
            f2v hlo = __builtin_shufflevector(hv, hv, 0, 1);                          \
            f2v hhi = __builtin_shufflevector(hv, hv, 2, 3);                          \
            acc0a = pkfma(wh0[2*m],   hlo, acc0a);                                    \
            acc1a = pkfma(wh1[2*m],   hlo, acc1a);                                    \
            acc0b = pkfma(wh0[2*m+1], hhi, acc0b);                                    \
            acc1b = pkfma(wh1[2*m+1], hhi, acc1b);                                    \
        }                                                                             \
        f2v acc0 = pkadd(acc0a, acc0b);                                               \
        f2v acc1 = pkadd(acc1a, acc1b);                                               \
        float a0 = acc0.x + acc0.y;                                                   \
        float a1 = acc1.x + acc1.y;                                                   \
        float s0 = __builtin_amdgcn_rcpf(1.f + __builtin_amdgcn_exp2f(a0 * CE));      \
        float s1 = __builtin_amdgcn_rcpf(1.f + __builtin_amdgcn_exp2f(a1 * c1));      \
        float t0 = __shfl_xor(s0, 32);                                                \
        float t1 = __shfl_xor(s1, 32);                                                \
        float si = hi ? t0 : s0;                                                      \
        float sf = hi ? s0 : t0;                                                      \
        float sg = hi ? t1 : s1;                                                      \
        float so = hi ? s1 : t1;                                                      \
        float tg = fmaf(2.f, sg, -1.f);                                               \
        c = fmaf(sf, c, si * tg);                                                     \
        float tc = fmaf(2.f, __builtin_amdgcn_rcpf(1.f + __builtin_amdgcn_exp2f(c * (2.f*CE))), -1.f); \
        float hval = so * tc;                                                         \
        if (!hi) lds_h[(WB) + j] = hval;                                              \
        else     hob[((T) << 5) + j] = hval;                                          \
    } while (0)

    // prefetch group 0
    f4v xa0 = xg[0], xa1 = xg[1], xa2 = xg[2];
#pragma unroll 1
    for (int t4 = 0; t4 < S_; t4 += 4) {
        const int gn = (t4 + 4 < S_) ? (3 * (t4 + 4) / 4) : (3 * t4 / 4);
        f4v xb0 = xg[gn], xb1 = xg[gn + 1], xb2 = xg[gn + 2];   // next-group prefetch
        STEP(t4 + 0, 0,  32, xa0.x, xa0.y, xa0.z);
        STEP(t4 + 1, 32, 0,  xa0.w, xa1.x, xa1.y);
        STEP(t4 + 2, 0,  32, xa1.z, xa1.w, xa2.x);
        STEP(t4 + 3, 32, 0,  xa2.y, xa2.z, xa2.w);
        xa0 = xb0; xa1 = xb1; xa2 = xb2;
    }
#undef STEP
}

// ---------------- final MLP: out = relu([a1,a2,h]@fc2^T+b2)@fc3^T+b3 ----------------
__global__ __launch_bounds__(256) void final_kernel(
    const float* __restrict__ h,      // (16,1024,32)
    const float* __restrict__ A,      // (2,16,3)
    const float* __restrict__ fc2_w,  // (16,38)
    const float* __restrict__ fc2_b,  // (16,)
    const float* __restrict__ fc3_w,  // (3,16)
    const float* __restrict__ fc3_b,  // (3,)
    float* __restrict__ out)          // (16,1024,3)
{
    __shared__ float sw2[16 * 38], sb2[16], sw3[48], sb3[3], sA[96];
    const int tid = threadIdx.x;
    for (int i = tid; i < 16 * 38; i += 256) sw2[i] = fc2_w[i];
    if (tid < 96) sA[tid] = A[tid];
    if (tid < 16) sb2[tid] = fc2_b[tid];
    if (tid < 48) sw3[tid] = fc3_w[tid];
    if (tid < 3)  sb3[tid] = fc3_b[tid];
    __syncthreads();

    const int p = blockIdx.x * 256 + tid;      // (b<<10)|s
    if (p >= B_ * S_) return;
    const int b = p >> 10;

    float hv[32];
    {
        const float4* hp = (const float4*)(h + ((size_t)p << 5));
#pragma unroll
        for (int m = 0; m < 8; ++m) {
            float4 t = hp[m];
            hv[4*m] = t.x; hv[4*m+1] = t.y; hv[4*m+2] = t.z; hv[4*m+3] = t.w;
        }
    }
    const float a10 = sA[b*3+0], a11 = sA[b*3+1], a12 = sA[b*3+2];
    const float a20 = sA[48+b*3+0], a21 = sA[48+b*3+1], a22 = sA[48+b*3+2];

    float y[16];
#pragma unroll
    for (int u = 0; u < 16; ++u) {
        const float* w = sw2 + u * 38;
        float acc = sb2[u];
        acc = fmaf(w[0], a10, acc); acc = fmaf(w[1], a11, acc); acc = fmaf(w[2], a12, acc);
        acc = fmaf(w[3], a20, acc); acc = fmaf(w[4], a21, acc); acc = fmaf(w[5], a22, acc);
#pragma unroll
        for (int k = 0; k < 32; ++k) acc = fmaf(w[6 + k], hv[k], acc);
        y[u] = fmaxf(acc, 0.f);
    }
#pragma unroll
    for (int d = 0; d < 3; ++d) {
        float o = sb3[d];
#pragma unroll
        for (int u = 0; u < 16; ++u) o = fmaf(sw3[d * 16 + u], y[u], o);
        out[p * 3 + d] = o;
    }
}

extern "C" void kernel_launch(void* const* d_in, const int* in_sizes, int n_in,
                              void* d_out, int out_size, void* d_ws, size_t ws_size,
                              hipStream_t stream) {
    const float* x      = (const float*)d_in[0];
    const float* v1     = (const float*)d_in[1];
    const float* v2     = (const float*)d_in[2];
    const float* attn_w = (const float*)d_in[3];
    // d_in[4] = attn_b: shift-invariant under softmax, unused
    const float* fc1_w  = (const float*)d_in[5];
    const float* fc1_b  = (const float*)d_in[6];
    const float* w_ih   = (const float*)d_in[7];
    const float* w_hh   = (const float*)d_in[8];
    const float* b_ih   = (const float*)d_in[9];
    const float* b_hh   = (const float*)d_in[10];
    const float* fc2_w  = (const float*)d_in[11];
    const float* fc2_b  = (const float*)d_in[12];
    const float* fc3_w  = (const float*)d_in[13];
    const float* fc3_b  = (const float*)d_in[14];
    float* out = (float*)d_out;

    float* Aws = (float*)d_ws;                         // 2*16*3 floats
    float* hws = (float*)((char*)d_ws + 4096);         // 16*1024*32 floats = 2 MiB

    fused_attn_lstm<<<48, 64, 0, stream>>>(x, v1, v2, attn_w, fc1_w, fc1_b,
                                           w_ih, w_hh, b_ih, b_hh, Aws, hws);
    final_kernel  <<<64, 256, 0, stream>>>(hws, Aws, fc2_w, fc2_b, fc3_w, fc3_b, out);
}